// Round 11
// baseline (86.307 us; speedup 1.0000x reference)
//
#include <hip/hip_runtime.h>
#include <hip/hip_bf16.h>

typedef _Float16 f16;
typedef f16 f16x4 __attribute__((ext_vector_type(4)));
typedef f16 f16x8 __attribute__((ext_vector_type(8)));
typedef float f32x4 __attribute__((ext_vector_type(4)));

#define DIM   768
#define NP    196
#define BATCH 64
#define MROWS (BATCH * NP)        // 12544
#define NCOLS (3 * DIM)           // 2304
#define GRIDF 14.0f

// ---------------- Kernel 1: f32 -> f16 conversion of x and [Wq;Wk;Wv] + bias array ----------------
#define NX4   (MROWS * DIM / 4)   // 2,408,448
#define NW4   (DIM * DIM / 4)     // 147,456 per W
#define NB4   (NCOLS / 4)         // 576
#define NCVTA (NX4 + 3 * NW4 + NB4)

__global__ __launch_bounds__(256) void convert_inputs(
    const float* __restrict__ x,
    const float* __restrict__ Wq, const float* __restrict__ Wk, const float* __restrict__ Wv,
    const float* __restrict__ bq, const float* __restrict__ bk, const float* __restrict__ bv,
    f16* __restrict__ x_h, f16* __restrict__ W_h, float* __restrict__ bias_all) {
  int i = blockIdx.x * 256 + threadIdx.x;
  if (i >= NCVTA) return;
  if (i < NX4 + 3 * NW4) {
    const float* src;
    f16* dst;
    int j;
    if (i < NX4) { src = x; dst = x_h; j = i; }
    else {
      j = i - NX4;
      if (j < NW4)          { src = Wq; dst = W_h; }
      else if (j < 2 * NW4) { src = Wk; dst = W_h + DIM * DIM;     j -= NW4; }
      else                  { src = Wv; dst = W_h + 2 * DIM * DIM; j -= 2 * NW4; }
    }
    float4 v = ((const float4*)src)[j];
    f16x4 h;
    h[0] = (f16)v.x; h[1] = (f16)v.y; h[2] = (f16)v.z; h[3] = (f16)v.w;
    ((f16x4*)dst)[j] = h;
  } else {
    int j = i - (NX4 + 3 * NW4);   // 0..575
    float4 v = (j < 192) ? ((const float4*)bq)[j]
             : (j < 384) ? ((const float4*)bk)[j - 192]
                         : ((const float4*)bv)[j - 384];
    ((float4*)bias_all)[j] = v;
  }
}

// ---------------- Kernel 2: qkv = x_h @ W_h^T + bias (224x256, BK=64, 8 waves, 504 blocks) -------
// Geometry: BM=224 (12544/224=56), BN=256 (2304/256=9) -> 504 blocks @ 1 block/CU
// = 98.4% dispatch packing (vs 441/512=86% at 256x256). 8 waves (2M x 4N), wave
// tile 112x64, acc[7][4]. LDS: sA 2x28KB + sB 2x32KB + 1KB scrap = 121 KB.
// A staging: waves 0-6 carry 4 real 16B chunks each (448x4x16B = 28KB exactly);
// wave 7 issues 4 DUMMY gl_lds (valid W-row source -> 1KB scrap) so every wave's
// vmcnt sees 8 issues/tile -> uniform counted waits.
// Schedule per K-tile (r10): 22 ds_reads (kh0's 11 first); lgkmcnt(11); 28 MFMA kh0;
// lgkmcnt(0); BAR; stage kt+2 (8 issues); 28 MFMA kh1; vmcnt(8) [drains kt+1]; BAR.
#define BM 224
#define BN 256
#define BK 64
#define NT (DIM / BK)   // 12

// LDS layout in f16 units
#define SA_SZ   (BM * BK)                 // 14336
#define SB_SZ   (BN * BK)                 // 16384
#define sAoff(buf) ((buf) * SA_SZ)
#define sBoff(buf) (2 * SA_SZ + (buf) * SB_SZ)
#define SCRAPF  (2 * SA_SZ + 2 * SB_SZ)   // 61440
#define LDS_F16 (SCRAPF + 512)            // 61952 f16 = 123904 B

__device__ __forceinline__ void gl_lds16(const f16* g, f16* l) {
  __builtin_amdgcn_global_load_lds(
      (const __attribute__((address_space(1))) void*)g,
      (__attribute__((address_space(3))) void*)l, 16, 0, 0);
}

#define MFMA16(acc_, av, bv) acc_ = __builtin_amdgcn_mfma_f32_16x16x32_f16(av, bv, acc_, 0, 0, 0)
#define BAR     __builtin_amdgcn_s_barrier()
#define LGKM11  asm volatile("s_waitcnt lgkmcnt(11)" ::: "memory")
#define LGKM0   asm volatile("s_waitcnt lgkmcnt(0)" ::: "memory")
#define VMCNT8  asm volatile("s_waitcnt vmcnt(8)" ::: "memory")
#define VMCNT0  asm volatile("s_waitcnt vmcnt(0)" ::: "memory")

__global__ __launch_bounds__(512, 2) void gemm_qkv(
    const f16* __restrict__ A, const f16* __restrict__ W,
    const float* __restrict__ bias_all, f16* __restrict__ C) {
  __shared__ __align__(16) f16 lds[LDS_F16];

  const int t    = threadIdx.x;
  const int lane = t & 63;
  const int wid  = t >> 6;
  const int wr   = wid >> 2;       // 0..1 (M)
  const int wc   = wid & 3;        // 0..3 (N)

  // XCD swizzle over 504 blocks (504 = 8*63, exact): logical = xcd*63 + seq; n fastest (9)
  const int xcd = blockIdx.x & 7, seq = blockIdx.x >> 3;
  const int logical = xcd * 63 + seq;
  const int bm0 = (logical / 9) * BM;
  const int bn0 = (logical % 9) * BN;

  // ---- A staging (waves 0-6 real, wave 7 dummy into scrap) ----
  const bool realA = (t < 448);
  const int arow  = realA ? (t >> 3) : 0;                 // 0..55
  const int aslot = t & 7;
  const int agcol = 8 * (aslot ^ (arow & 7));             // pre-swizzled source col
  const f16* gA_base = realA ? (A + (size_t)(bm0 + arow) * DIM + agcol)
                             : (W + (size_t)(bn0 + lane) * DIM);  // dummy: valid W row
  const int aoff_rel   = realA ? (arow * BK + aslot * 8) : (lane * 8);  // lane-linear per wave
  const size_t a_gstr  = realA ? (size_t)56 * DIM : 0;    // +56 rows per issue (dummy: stay)
  const int    a_lstr  = realA ? 56 * BK : 0;

#define STAGE_A(kt) do {                                                       \
    const f16* _g = gA_base + (kt) * BK;                                       \
    f16* _l = &lds[(realA ? sAoff((kt) & 1) : SCRAPF) + aoff_rel];             \
    gl_lds16(_g,              _l);                                             \
    gl_lds16(_g + a_gstr,     _l + a_lstr);                                    \
    gl_lds16(_g + 2 * a_gstr, _l + 2 * a_lstr);                                \
    gl_lds16(_g + 3 * a_gstr, _l + 3 * a_lstr);                                \
  } while (0)

  // ---- B staging (uniform, 256 rows = 4 x 64-row chunks) ----
  const int brow  = t >> 3;                                // 0..63
  const int bslot = t & 7;
  const int bgcol = 8 * (bslot ^ (brow & 7));
  const f16* gB_base = W + (size_t)(bn0 + brow) * DIM + bgcol;
  const int boff = brow * BK + bslot * 8;

#define STAGE_B(kt) do {                                                       \
    const f16* _g = gB_base + (kt) * BK;                                       \
    f16* _l = &lds[sBoff((kt) & 1) + boff];                                    \
    gl_lds16(_g,                      _l);                                     \
    gl_lds16(_g + (size_t)64  * DIM,  _l + 64  * BK);                          \
    gl_lds16(_g + (size_t)128 * DIM,  _l + 128 * BK);                          \
    gl_lds16(_g + (size_t)192 * DIM,  _l + 192 * BK);                          \
  } while (0)

  // ---- Fragment-read coords: slot = ((kh*4 + kg) ^ (lane&7)) * 8 ----
  const int rl = lane & 15;
  const int kg = lane >> 4;        // 0..3
  const int s7 = lane & 7;
  const int slot0 = ((0 * 4 + kg) ^ s7) * 8;
  const int slot1 = ((1 * 4 + kg) ^ s7) * 8;
  const int aBase = (wr * 112 + rl) * BK;   // 112 % 8 == 0 -> swizzle periodicity holds
  const int bBase = (wc * 64 + rl) * BK;

  f32x4 acc[7][4] = {};
  f16x8 afr[7][2], bfr[4][2];

  // kh0 set (11 reads) issued FIRST -> lgkmcnt(11) == kh0 resident
#define LDAB_KH0(buf) do {                                                              \
    _Pragma("unroll") for (int ni = 0; ni < 4; ++ni)                                    \
      bfr[ni][0] = *(const f16x8*)&lds[sBoff(buf) + bBase + ni * 16 * BK + slot0];      \
    _Pragma("unroll") for (int mi = 0; mi < 7; ++mi)                                    \
      afr[mi][0] = *(const f16x8*)&lds[sAoff(buf) + aBase + mi * 16 * BK + slot0];      \
    } while (0)

#define LDAB_KH1(buf) do {                                                              \
    _Pragma("unroll") for (int ni = 0; ni < 4; ++ni)                                    \
      bfr[ni][1] = *(const f16x8*)&lds[sBoff(buf) + bBase + ni * 16 * BK + slot1];      \
    _Pragma("unroll") for (int mi = 0; mi < 7; ++mi)                                    \
      afr[mi][1] = *(const f16x8*)&lds[sAoff(buf) + aBase + mi * 16 * BK + slot1];      \
    } while (0)

  // SWAPPED operand order: mfma(bfr, afr) -> m = lane&15 (A row), n = 4*kg + reg (B row)
#define MMA_KH(kh) do {                                                          \
    __builtin_amdgcn_s_setprio(1);                                               \
    _Pragma("unroll") for (int ni = 0; ni < 4; ++ni)                             \
      _Pragma("unroll") for (int mi = 0; mi < 7; ++mi)                           \
        MFMA16(acc[mi][ni], bfr[ni][kh], afr[mi][kh]);                           \
    __builtin_amdgcn_s_setprio(0); } while (0)

  // ---- Prologue: stage tiles 0,1 (8 issues each); drain tile0, tile1 in flight
  STAGE_A(0); STAGE_B(0);
  STAGE_A(1); STAGE_B(1);
  VMCNT8;
  BAR;

  for (int kt = 0; kt < NT; ++kt) {
    const int b = kt & 1;
    const bool more = (kt + 2 < NT);
    LDAB_KH0(b);
    LDAB_KH1(b);
    LGKM11;             // kh0 fragments resident; kh1 still draining
    MMA_KH(0);
    LGKM0; BAR;         // all waves' reads of buf b complete -> buf b reusable
    if (more) { STAGE_A(kt + 2); STAGE_B(kt + 2); }
    MMA_KH(1);
    if (more) { VMCNT8; } else { VMCNT0; }   // tile kt+1 landed (kt+2's 8 stay in flight)
    BAR;
  }

  // ---- Epilogue: acc -> swizzled LDS C-tile (224x256 f16 = 112KB, bias fused) -> coalesced stores
  // m = bm0 + wr*112 + mi*16 + rl ; n = bn0 + wc*64 + ni*16 + 4*kg + v
  {
    const int eRow0 = wr * 112 + rl;
    const int nq0   = wc * 64 + 4 * kg;
#pragma unroll
    for (int ni = 0; ni < 4; ++ni) {
      const int nloc = nq0 + ni * 16;
      const float4 b4 = *(const float4*)&bias_all[bn0 + nloc];
#pragma unroll
      for (int mi = 0; mi < 7; ++mi) {
        const int e = eRow0 + mi * 16;
        f16x4 h;
        h[0] = (f16)(acc[mi][ni][0] + b4.x);
        h[1] = (f16)(acc[mi][ni][1] + b4.y);
        h[2] = (f16)(acc[mi][ni][2] + b4.z);
        h[3] = (f16)(acc[mi][ni][3] + b4.w);
        *(f16x4*)&lds[e * 256 + (nloc ^ ((e & 7) << 3))] = h;
      }
    }
    LGKM0; BAR;
    const int rrow = t >> 5;       // 0..15
    const int rchk = t & 31;       // 0..31, 8 f16 each (256 f16/row)
#pragma unroll
    for (int p = 0; p < 14; ++p) { // 14*16 = 224 rows
      const int row = p * 16 + rrow;
      f16x8 vdat = *(const f16x8*)&lds[row * 256 + ((rchk * 8) ^ ((row & 7) << 3))];
      *(f16x8*)&C[(size_t)(bm0 + row) * NCOLS + bn0 + rchk * 8] = vdat;
    }
  }
}

// ---------------- Kernel 3: gather + 4-way per-feature softmax + weighted sum ----------------
// XCD-chunked block swizzle: 3136 blocks = 8 * 392; each XCD gets 392 consecutive blocks.
__global__ __launch_bounds__(256) void attend(
    const f16* __restrict__ qkv,
    const int* __restrict__ img_ids, const float* __restrict__ eps,
    const float* __restrict__ avgs, const float* __restrict__ stds,
    float* __restrict__ out) {
  const int lane = threadIdx.x & 63;
  const int wid  = threadIdx.x >> 6;
  const int logical = (blockIdx.x & 7) * 392 + (blockIdx.x >> 3);
  const int gw = logical * 4 + wid;          // (b*196 + s)
  const int b = gw / NP;
  const int s = gw - b * NP;

  const int img = img_ids[b];
  const float ex = eps[(b * 2 + 0) * NP + s];
  const float ey = eps[(b * 2 + 1) * NP + s];
  const float mux = avgs[(img * 2 + 0) * NP + s];
  const float muy = avgs[(img * 2 + 1) * NP + s];
  const float sdx = stds[(img * 2 + 0) * NP + s];
  const float sdy = stds[(img * 2 + 1) * NP + s];

  const float kx = fmaf(sdx, ex, mux);
  const float ky = fmaf(sdy, ey, muy);
  const float kx1 = ceilf(kx), kx2 = floorf(kx);
  const float ky1 = ceilf(ky), ky2 = floorf(ky);

  int idx[4];
  idx[0] = (int)fminf(fmaxf(GRIDF * ky1 + kx1, 0.0f), 195.0f);
  idx[1] = (int)fminf(fmaxf(GRIDF * ky1 + kx2, 0.0f), 195.0f);
  idx[2] = (int)fminf(fmaxf(GRIDF * ky2 + kx1, 0.0f), 195.0f);
  idx[3] = (int)fminf(fmaxf(GRIDF * ky2 + kx2, 0.0f), 195.0f);

  const f16* qrow = qkv + (size_t)gw * NCOLS;
  const f16* base = qkv + (size_t)(b * NP) * NCOLS;
  const f16* k0p = base + (size_t)idx[0] * NCOLS + DIM;
  const f16* k1p = base + (size_t)idx[1] * NCOLS + DIM;
  const f16* k2p = base + (size_t)idx[2] * NCOLS + DIM;
  const f16* k3p = base + (size_t)idx[3] * NCOLS + DIM;
  const f16* v0p = k0p + DIM;
  const f16* v1p = k1p + DIM;
  const f16* v2p = k2p + DIM;
  const f16* v3p = k3p + DIM;
  float* orow = out + (size_t)gw * DIM;

#pragma unroll
  for (int seg = 0; seg < 3; ++seg) {
    const int e0 = seg * 256 + lane * 4;
    f16x4 qv  = *(const f16x4*)(qrow + e0);
    f16x4 kv0 = *(const f16x4*)(k0p + e0);
    f16x4 kv1 = *(const f16x4*)(k1p + e0);
    f16x4 kv2 = *(const f16x4*)(k2p + e0);
    f16x4 kv3 = *(const f16x4*)(k3p + e0);
    f16x4 vv0 = *(const f16x4*)(v0p + e0);
    f16x4 vv1 = *(const f16x4*)(v1p + e0);
    f16x4 vv2 = *(const f16x4*)(v2p + e0);
    f16x4 vv3 = *(const f16x4*)(v3p + e0);
    float4 o;
    float* op = &o.x;
#pragma unroll
    for (int c = 0; c < 4; ++c) {
      const float q = (float)qv[c];
      const float s0 = q * (float)kv0[c];
      const float s1 = q * (float)kv1[c];
      const float s2 = q * (float)kv2[c];
      const float s3 = q * (float)kv3[c];
      const float mx = fmaxf(fmaxf(s0, s1), fmaxf(s2, s3));
      const float w0 = __expf(s0 - mx);
      const float w1 = __expf(s1 - mx);
      const float w2 = __expf(s2 - mx);
      const float w3 = __expf(s3 - mx);
      const float den = w0 + w1 + w2 + w3;
      const float num = w0 * (float)vv0[c] + w1 * (float)vv1[c] +
                        w2 * (float)vv2[c] + w3 * (float)vv3[c];
      op[c] = num / den;
    }
    *(float4*)(orow + e0) = o;
  }
}

// ---------------- Launch ----------------
extern "C" void kernel_launch(void* const* d_in, const int* in_sizes, int n_in,
                              void* d_out, int out_size, void* d_ws, size_t ws_size,
                              hipStream_t stream) {
  const float* x       = (const float*)d_in[0];
  const int*   img_ids = (const int*)d_in[2];
  const float* eps     = (const float*)d_in[3];
  const float* Wq      = (const float*)d_in[4];
  const float* bq      = (const float*)d_in[5];
  const float* Wk      = (const float*)d_in[6];
  const float* bk      = (const float*)d_in[7];
  const float* Wv      = (const float*)d_in[8];
  const float* bv      = (const float*)d_in[9];
  const float* avgs    = (const float*)d_in[10];
  const float* stds    = (const float*)d_in[11];
  float* out = (float*)d_out;

  char* ws = (char*)d_ws;
  const size_t XH_BYTES = (size_t)MROWS * DIM * 2;   // 19,267,584
  const size_t WH_BYTES = (size_t)NCOLS * DIM * 2;   //  3,538,944
  const size_t BI_BYTES = (size_t)NCOLS * 4;         //      9,216
  f16*   x_h      = (f16*)ws;
  f16*   W_h      = (f16*)(ws + XH_BYTES);
  float* bias_all = (float*)(ws + XH_BYTES + WH_BYTES);
  f16*   qkv      = (f16*)(ws + XH_BYTES + WH_BYTES + BI_BYTES);

  {
    int grid = (NCVTA + 255) / 256;
    convert_inputs<<<grid, 256, 0, stream>>>(x, Wq, Wk, Wv, bq, bk, bv, x_h, W_h, bias_all);
  }
  {
    gemm_qkv<<<504, 512, 0, stream>>>(x_h, W_h, bias_all, qkv);
  }
  {
    int grid = MROWS / 4;
    attend<<<grid, 256, 0, stream>>>(qkv, img_ids, eps, avgs, stds, out);
  }
}